// Round 1
// baseline (2856.350 us; speedup 1.0000x reference)
//
#include <hip/hip_runtime.h>

#define N_NODES_C 100000
#define N_EDGES_C 1600000
#define D_C 128

// ---------------------------------------------------------------------------
// K1: Y = X @ W^T   (W is [D_OUT, D_IN] row-major; Y[n,o] = sum_k X[n,k]*W[o,k])
// Block: 256 threads, tile = 64 rows x 128 cols. W^T staged in LDS (stride 132
// floats keeps float4 reads 16B-aligned and write conflicts to 4-way).
// Each thread: 8 rows x 4 cols of output, k-loop unrolled by 4 with float4 X loads.
// ---------------------------------------------------------------------------
__global__ __launch_bounds__(256) void gemm_xwt(const float* __restrict__ X,
                                                const float* __restrict__ W,
                                                float* __restrict__ Y, int n) {
    __shared__ float Wt[128 * 132];  // Wt[k*132 + o] = W[o*128 + k]

    for (int idx = threadIdx.x; idx < 128 * 128; idx += 256) {
        int o = idx >> 7;
        int k = idx & 127;
        Wt[k * 132 + o] = W[idx];
    }
    __syncthreads();

    const int c = threadIdx.x & 31;   // col group: cols 4c..4c+3
    const int r = threadIdx.x >> 5;   // row group: rows r*8..r*8+7 within tile
    const long row0 = (long)blockIdx.x * 64;

    // Clamped row pointers (loads always in-bounds; stores guarded)
    const float* xrow[8];
#pragma unroll
    for (int i = 0; i < 8; ++i) {
        long nr = row0 + r * 8 + i;
        if (nr >= n) nr = n - 1;
        xrow[i] = X + nr * D_C;
    }

    float acc[8][4];
#pragma unroll
    for (int i = 0; i < 8; ++i)
#pragma unroll
        for (int j = 0; j < 4; ++j) acc[i][j] = 0.f;

    for (int k4 = 0; k4 < 128; k4 += 4) {
        float4 w0 = *(const float4*)&Wt[(k4 + 0) * 132 + 4 * c];
        float4 w1 = *(const float4*)&Wt[(k4 + 1) * 132 + 4 * c];
        float4 w2 = *(const float4*)&Wt[(k4 + 2) * 132 + 4 * c];
        float4 w3 = *(const float4*)&Wt[(k4 + 3) * 132 + 4 * c];
#pragma unroll
        for (int i = 0; i < 8; ++i) {
            float4 xv = *(const float4*)&xrow[i][k4];
            acc[i][0] += xv.x * w0.x + xv.y * w1.x + xv.z * w2.x + xv.w * w3.x;
            acc[i][1] += xv.x * w0.y + xv.y * w1.y + xv.z * w2.y + xv.w * w3.y;
            acc[i][2] += xv.x * w0.z + xv.y * w1.z + xv.z * w2.z + xv.w * w3.z;
            acc[i][3] += xv.x * w0.w + xv.y * w1.w + xv.z * w2.w + xv.w * w3.w;
        }
    }

#pragma unroll
    for (int i = 0; i < 8; ++i) {
        long nr = row0 + r * 8 + i;
        if (nr < n) {
            float4 v = make_float4(acc[i][0], acc[i][1], acc[i][2], acc[i][3]);
            *(float4*)&Y[nr * D_C + 4 * c] = v;
        }
    }
}

// ---------------------------------------------------------------------------
// K2: out[n, :] = b[:]   (one float4 per thread)
// ---------------------------------------------------------------------------
__global__ __launch_bounds__(256) void init_out(const float* __restrict__ b,
                                                float* __restrict__ out, int n) {
    int idx = blockIdx.x * 256 + threadIdx.x;
    int total = n * (D_C / 4);
    if (idx < total) {
        int o4 = idx & (D_C / 4 - 1);
        float4 bv = ((const float4*)b)[o4];
        ((float4*)out)[idx] = bv;
    }
}

// ---------------------------------------------------------------------------
// K3: out[row] += val * Y[col]  — 32 lanes per edge, float4 per lane,
// hardware fp32 atomics (unsafeAtomicAdd -> global_atomic_add_f32).
// ---------------------------------------------------------------------------
__global__ __launch_bounds__(256) void scatter_edges(const int* __restrict__ rows,
                                                     const int* __restrict__ cols,
                                                     const float* __restrict__ vals,
                                                     const float* __restrict__ Y,
                                                     float* __restrict__ out, int E) {
    int e = blockIdx.x * 8 + (threadIdx.x >> 5);
    if (e >= E) return;
    int lane = threadIdx.x & 31;

    int row = rows[e];
    int col = cols[e];
    float v = vals[e];

    float4 y = *(const float4*)&Y[(long)col * D_C + lane * 4];
    float* dst = out + (long)row * D_C + lane * 4;
    unsafeAtomicAdd(dst + 0, v * y.x);
    unsafeAtomicAdd(dst + 1, v * y.y);
    unsafeAtomicAdd(dst + 2, v * y.z);
    unsafeAtomicAdd(dst + 3, v * y.w);
}

extern "C" void kernel_launch(void* const* d_in, const int* in_sizes, int n_in,
                              void* d_out, int out_size, void* d_ws, size_t ws_size,
                              hipStream_t stream) {
    const float* X  = (const float*)d_in[0];
    const int*   Ar = (const int*)d_in[1];
    const int*   Ac = (const int*)d_in[2];
    const float* Av = (const float*)d_in[3];
    const float* W  = (const float*)d_in[4];
    const float* b  = (const float*)d_in[5];
    float* out = (float*)d_out;
    float* Y   = (float*)d_ws;  // N_NODES * 128 floats = 51.2 MB scratch

    // Y = X @ W^T
    gemm_xwt<<<(N_NODES_C + 63) / 64, 256, 0, stream>>>(X, W, Y, N_NODES_C);
    // out = b (broadcast)
    init_out<<<(N_NODES_C * (D_C / 4) + 255) / 256, 256, 0, stream>>>(b, out, N_NODES_C);
    // out[row] += val * Y[col]
    scatter_edges<<<(N_EDGES_C + 7) / 8, 256, 0, stream>>>(Ar, Ac, Av, Y, out, N_EDGES_C);
}

// Round 2
// 691.681 us; speedup vs baseline: 4.1296x; 4.1296x over previous
//
#include <hip/hip_runtime.h>

#define N_NODES_C 100000
#define N_EDGES_C 1600000
#define D_C 128
#define SCAN_T 1024

// ---------------------------------------------------------------------------
// K1: Y = X @ W^T   (W is [D_OUT, D_IN] row-major; Y[n,o] = sum_k X[n,k]*W[o,k])
// ---------------------------------------------------------------------------
__global__ __launch_bounds__(256) void gemm_xwt(const float* __restrict__ X,
                                                const float* __restrict__ W,
                                                float* __restrict__ Y, int n) {
    __shared__ float Wt[128 * 132];  // Wt[k*132 + o] = W[o*128 + k]

    for (int idx = threadIdx.x; idx < 128 * 128; idx += 256) {
        int o = idx >> 7;
        int k = idx & 127;
        Wt[k * 132 + o] = W[idx];
    }
    __syncthreads();

    const int c = threadIdx.x & 31;   // cols 4c..4c+3
    const int r = threadIdx.x >> 5;   // rows r*8..r*8+7 within tile
    const long row0 = (long)blockIdx.x * 64;

    const float* xrow[8];
#pragma unroll
    for (int i = 0; i < 8; ++i) {
        long nr = row0 + r * 8 + i;
        if (nr >= n) nr = n - 1;
        xrow[i] = X + nr * D_C;
    }

    float acc[8][4];
#pragma unroll
    for (int i = 0; i < 8; ++i)
#pragma unroll
        for (int j = 0; j < 4; ++j) acc[i][j] = 0.f;

    for (int k4 = 0; k4 < 128; k4 += 4) {
        float4 w0 = *(const float4*)&Wt[(k4 + 0) * 132 + 4 * c];
        float4 w1 = *(const float4*)&Wt[(k4 + 1) * 132 + 4 * c];
        float4 w2 = *(const float4*)&Wt[(k4 + 2) * 132 + 4 * c];
        float4 w3 = *(const float4*)&Wt[(k4 + 3) * 132 + 4 * c];
#pragma unroll
        for (int i = 0; i < 8; ++i) {
            float4 xv = *(const float4*)&xrow[i][k4];
            acc[i][0] += xv.x * w0.x + xv.y * w1.x + xv.z * w2.x + xv.w * w3.x;
            acc[i][1] += xv.x * w0.y + xv.y * w1.y + xv.z * w2.y + xv.w * w3.y;
            acc[i][2] += xv.x * w0.z + xv.y * w1.z + xv.z * w2.z + xv.w * w3.z;
            acc[i][3] += xv.x * w0.w + xv.y * w1.w + xv.z * w2.w + xv.w * w3.w;
        }
    }

#pragma unroll
    for (int i = 0; i < 8; ++i) {
        long nr = row0 + r * 8 + i;
        if (nr < n) {
            float4 v = make_float4(acc[i][0], acc[i][1], acc[i][2], acc[i][3]);
            *(float4*)&Y[nr * D_C + 4 * c] = v;
        }
    }
}

// ---------------------------------------------------------------------------
// CSR build: histogram -> single-block chunked scan -> bucket fill
// ---------------------------------------------------------------------------
__global__ __launch_bounds__(256) void hist_rows(const int* __restrict__ rows,
                                                 int* __restrict__ cnt, int E) {
    int e = blockIdx.x * 256 + threadIdx.x;
    if (e < E) atomicAdd(&cnt[rows[e]], 1);
}

// Single block, 1024 threads. Each thread owns a contiguous chunk: local sum,
// block-wide Hillis-Steele over the 1024 chunk sums, then sequential exclusive
// prefixes within the chunk. Writes both row_start and cursor.
__global__ __launch_bounds__(SCAN_T) void scan_counts(const int* __restrict__ cnt,
                                                      int* __restrict__ start,
                                                      int* __restrict__ cursor, int n) {
    __shared__ int sums[SCAN_T];
    const int tid = threadIdx.x;
    const int C = (n + SCAN_T - 1) / SCAN_T;
    const int lo = tid * C;
    const int hi = (lo + C < n) ? lo + C : n;

    int s = 0;
    for (int i = lo; i < hi; ++i) s += cnt[i];
    sums[tid] = s;
    __syncthreads();

    for (int off = 1; off < SCAN_T; off <<= 1) {
        int t = (tid >= off) ? sums[tid - off] : 0;
        __syncthreads();
        sums[tid] += t;
        __syncthreads();
    }

    int run = (tid > 0) ? sums[tid - 1] : 0;
    for (int i = lo; i < hi; ++i) {
        start[i] = run;
        cursor[i] = run;
        run += cnt[i];
    }
    if (tid == SCAN_T - 1) start[n] = sums[SCAN_T - 1];
}

__global__ __launch_bounds__(256) void fill_csr(const int* __restrict__ rows,
                                                const int* __restrict__ cols,
                                                const float* __restrict__ vals,
                                                int* __restrict__ cursor,
                                                int* __restrict__ pcol,
                                                float* __restrict__ pval, int E) {
    int e = blockIdx.x * 256 + threadIdx.x;
    if (e >= E) return;
    int r = rows[e];
    int slot = atomicAdd(&cursor[r], 1);
    pcol[slot] = cols[e];
    pval[slot] = vals[e];
}

// ---------------------------------------------------------------------------
// K3: pull aggregation. One wave (64 lanes) per row, float2 per lane.
// out[row] = b + sum_{i in row} val[i] * Y[col[i]]   (no atomics, one write)
// ---------------------------------------------------------------------------
__global__ __launch_bounds__(256) void aggregate(const int* __restrict__ start,
                                                 const int* __restrict__ pcol,
                                                 const float* __restrict__ pval,
                                                 const float* __restrict__ Y,
                                                 const float* __restrict__ b,
                                                 float* __restrict__ out, int n) {
    int row = blockIdx.x * 4 + (threadIdx.x >> 6);
    if (row >= n) return;
    int lane = threadIdx.x & 63;

    int s = start[row];
    int e = start[row + 1];
    float2 acc = *(const float2*)&b[lane * 2];

    int i = s;
    for (; i + 2 <= e; i += 2) {  // unroll 2: two independent gathers in flight
        int c0 = pcol[i];
        int c1 = pcol[i + 1];
        float v0 = pval[i];
        float v1 = pval[i + 1];
        float2 y0 = *(const float2*)&Y[(long)c0 * D_C + lane * 2];
        float2 y1 = *(const float2*)&Y[(long)c1 * D_C + lane * 2];
        acc.x += v0 * y0.x + v1 * y1.x;
        acc.y += v0 * y0.y + v1 * y1.y;
    }
    if (i < e) {
        int c0 = pcol[i];
        float v0 = pval[i];
        float2 y0 = *(const float2*)&Y[(long)c0 * D_C + lane * 2];
        acc.x += v0 * y0.x;
        acc.y += v0 * y0.y;
    }
    *(float2*)&out[(long)row * D_C + lane * 2] = acc;
}

// ---------------------------------------------------------------------------
// Fallback path (only if ws_size < CSR layout): round-1 atomic scatter.
// ---------------------------------------------------------------------------
__global__ __launch_bounds__(256) void init_out(const float* __restrict__ b,
                                                float* __restrict__ out, int n) {
    int idx = blockIdx.x * 256 + threadIdx.x;
    int total = n * (D_C / 4);
    if (idx < total) {
        int o4 = idx & (D_C / 4 - 1);
        ((float4*)out)[idx] = ((const float4*)b)[o4];
    }
}

__global__ __launch_bounds__(256) void scatter_edges(const int* __restrict__ rows,
                                                     const int* __restrict__ cols,
                                                     const float* __restrict__ vals,
                                                     const float* __restrict__ Y,
                                                     float* __restrict__ out, int E) {
    int e = blockIdx.x * 8 + (threadIdx.x >> 5);
    if (e >= E) return;
    int lane = threadIdx.x & 31;
    int row = rows[e];
    int col = cols[e];
    float v = vals[e];
    float4 y = *(const float4*)&Y[(long)col * D_C + lane * 4];
    float* dst = out + (long)row * D_C + lane * 4;
    unsafeAtomicAdd(dst + 0, v * y.x);
    unsafeAtomicAdd(dst + 1, v * y.y);
    unsafeAtomicAdd(dst + 2, v * y.z);
    unsafeAtomicAdd(dst + 3, v * y.w);
}

extern "C" void kernel_launch(void* const* d_in, const int* in_sizes, int n_in,
                              void* d_out, int out_size, void* d_ws, size_t ws_size,
                              hipStream_t stream) {
    const float* X  = (const float*)d_in[0];
    const int*   Ar = (const int*)d_in[1];
    const int*   Ac = (const int*)d_in[2];
    const float* Av = (const float*)d_in[3];
    const float* W  = (const float*)d_in[4];
    const float* b  = (const float*)d_in[5];
    float* out = (float*)d_out;

    // Workspace layout (4B elements), all 256B-aligned strides:
    //   Y      : 12,800,000 f32
    //   cnt    : 100,096 i32
    //   start  : 100,096 i32 (uses N+1)
    //   cursor : 100,096 i32
    //   pcol   : 1,600,000 i32
    //   pval   : 1,600,000 f32
    float* Y    = (float*)d_ws;
    int* cnt    = (int*)(Y + 12800000);
    int* start  = cnt + 100096;
    int* cursor = start + 100096;
    int* pcol   = cursor + 100096;
    float* pval = (float*)(pcol + 1600000);
    size_t need = (size_t)(12800000 + 3 * 100096 + 2 * 1600000) * 4;

    // Y = X @ W^T (shared by both paths)
    gemm_xwt<<<(N_NODES_C + 63) / 64, 256, 0, stream>>>(X, W, Y, N_NODES_C);

    if (ws_size >= need) {
        // --- CSR build ---
        hipMemsetAsync(cnt, 0, N_NODES_C * sizeof(int), stream);
        hist_rows<<<(N_EDGES_C + 255) / 256, 256, 0, stream>>>(Ar, cnt, N_EDGES_C);
        scan_counts<<<1, SCAN_T, 0, stream>>>(cnt, start, cursor, N_NODES_C);
        fill_csr<<<(N_EDGES_C + 255) / 256, 256, 0, stream>>>(Ar, Ac, Av, cursor,
                                                              pcol, pval, N_EDGES_C);
        // --- pull aggregation, bias fused ---
        aggregate<<<(N_NODES_C + 3) / 4, 256, 0, stream>>>(start, pcol, pval, Y, b,
                                                           out, N_NODES_C);
    } else {
        // Fallback: atomic scatter (round-1 path)
        init_out<<<(N_NODES_C * (D_C / 4) + 255) / 256, 256, 0, stream>>>(b, out, N_NODES_C);
        scatter_edges<<<(N_EDGES_C + 7) / 8, 256, 0, stream>>>(Ar, Ac, Av, Y, out, N_EDGES_C);
    }
}

// Round 3
// 469.985 us; speedup vs baseline: 6.0775x; 1.4717x over previous
//
#include <hip/hip_runtime.h>

#define N_NODES_C 100000
#define N_EDGES_C 1600000
#define D_C 128
#define NB_SCAN ((N_NODES_C + 255) / 256)   // 391 blocks for the scan

// ---------------------------------------------------------------------------
// K1: Y = X @ W^T   (W is [D_OUT, D_IN] row-major; Y[n,o] = sum_k X[n,k]*W[o,k])
// ---------------------------------------------------------------------------
__global__ __launch_bounds__(256) void gemm_xwt(const float* __restrict__ X,
                                                const float* __restrict__ W,
                                                float* __restrict__ Y, int n) {
    __shared__ float Wt[128 * 132];  // Wt[k*132 + o] = W[o*128 + k]

    for (int idx = threadIdx.x; idx < 128 * 128; idx += 256) {
        int o = idx >> 7;
        int k = idx & 127;
        Wt[k * 132 + o] = W[idx];
    }
    __syncthreads();

    const int c = threadIdx.x & 31;   // cols 4c..4c+3
    const int r = threadIdx.x >> 5;   // rows r*8..r*8+7 within tile
    const long row0 = (long)blockIdx.x * 64;

    const float* xrow[8];
#pragma unroll
    for (int i = 0; i < 8; ++i) {
        long nr = row0 + r * 8 + i;
        if (nr >= n) nr = n - 1;
        xrow[i] = X + nr * D_C;
    }

    float acc[8][4];
#pragma unroll
    for (int i = 0; i < 8; ++i)
#pragma unroll
        for (int j = 0; j < 4; ++j) acc[i][j] = 0.f;

    for (int k4 = 0; k4 < 128; k4 += 4) {
        float4 w0 = *(const float4*)&Wt[(k4 + 0) * 132 + 4 * c];
        float4 w1 = *(const float4*)&Wt[(k4 + 1) * 132 + 4 * c];
        float4 w2 = *(const float4*)&Wt[(k4 + 2) * 132 + 4 * c];
        float4 w3 = *(const float4*)&Wt[(k4 + 3) * 132 + 4 * c];
#pragma unroll
        for (int i = 0; i < 8; ++i) {
            float4 xv = *(const float4*)&xrow[i][k4];
            acc[i][0] += xv.x * w0.x + xv.y * w1.x + xv.z * w2.x + xv.w * w3.x;
            acc[i][1] += xv.x * w0.y + xv.y * w1.y + xv.z * w2.y + xv.w * w3.y;
            acc[i][2] += xv.x * w0.z + xv.y * w1.z + xv.z * w2.z + xv.w * w3.z;
            acc[i][3] += xv.x * w0.w + xv.y * w1.w + xv.z * w2.w + xv.w * w3.w;
        }
    }

#pragma unroll
    for (int i = 0; i < 8; ++i) {
        long nr = row0 + r * 8 + i;
        if (nr < n) {
            float4 v = make_float4(acc[i][0], acc[i][1], acc[i][2], acc[i][3]);
            *(float4*)&Y[nr * D_C + 4 * c] = v;
        }
    }
}

// ---------------------------------------------------------------------------
// CSR build: histogram -> 3-kernel parallel scan -> bucket fill
// ---------------------------------------------------------------------------
__global__ __launch_bounds__(256) void hist_rows(const int* __restrict__ rows,
                                                 int* __restrict__ cnt, int E) {
    int e = blockIdx.x * 256 + threadIdx.x;
    if (e < E) atomicAdd(&cnt[rows[e]], 1);
}

// K2a: partial[b] = sum of cnt[b*256 .. b*256+255]
__global__ __launch_bounds__(256) void block_sums(const int* __restrict__ cnt,
                                                  int* __restrict__ partial, int n) {
    __shared__ int buf[256];
    int i = blockIdx.x * 256 + threadIdx.x;
    buf[threadIdx.x] = (i < n) ? cnt[i] : 0;
    __syncthreads();
#pragma unroll
    for (int off = 128; off > 0; off >>= 1) {
        if (threadIdx.x < off) buf[threadIdx.x] += buf[threadIdx.x + off];
        __syncthreads();
    }
    if (threadIdx.x == 0) partial[blockIdx.x] = buf[0];
}

// K2b: exclusive scan of partial[0..nb) (nb <= 512), one block, all in LDS.
__global__ __launch_bounds__(512) void scan_partials(const int* __restrict__ partial,
                                                     int* __restrict__ pscan, int nb) {
    __shared__ int buf[512];
    int tid = threadIdx.x;
    int v = (tid < nb) ? partial[tid] : 0;
    buf[tid] = v;
    __syncthreads();
#pragma unroll
    for (int off = 1; off < 512; off <<= 1) {
        int t = (tid >= off) ? buf[tid - off] : 0;
        __syncthreads();
        buf[tid] += t;
        __syncthreads();
    }
    if (tid < nb) pscan[tid] = buf[tid] - v;  // exclusive
}

// K2c: block-local exclusive scan of cnt + block offset -> start, cursor.
__global__ __launch_bounds__(256) void scan_block(const int* __restrict__ cnt,
                                                  const int* __restrict__ pscan,
                                                  int* __restrict__ start,
                                                  int* __restrict__ cursor, int n) {
    __shared__ int buf[256];
    int i = blockIdx.x * 256 + threadIdx.x;
    int tid = threadIdx.x;
    int v = (i < n) ? cnt[i] : 0;
    buf[tid] = v;
    __syncthreads();
#pragma unroll
    for (int off = 1; off < 256; off <<= 1) {
        int t = (tid >= off) ? buf[tid - off] : 0;
        __syncthreads();
        buf[tid] += t;
        __syncthreads();
    }
    int excl = buf[tid] - v + pscan[blockIdx.x];
    if (i < n) {
        start[i] = excl;
        cursor[i] = excl;
    }
    if (i == n - 1) start[n] = N_EDGES_C;  // total is a compile-time constant
}

__global__ __launch_bounds__(256) void fill_csr(const int* __restrict__ rows,
                                                const int* __restrict__ cols,
                                                const float* __restrict__ vals,
                                                int* __restrict__ cursor,
                                                int* __restrict__ pcol,
                                                float* __restrict__ pval, int E) {
    int e = blockIdx.x * 256 + threadIdx.x;
    if (e >= E) return;
    int r = rows[e];
    int slot = atomicAdd(&cursor[r], 1);
    pcol[slot] = cols[e];
    pval[slot] = vals[e];
}

// ---------------------------------------------------------------------------
// K3: pull aggregation. 32 lanes per row, float4 per lane, unroll-4 edge loop.
// out[row] = b + sum_{i in row} val[i] * Y[col[i]]   (no atomics, one write)
// ---------------------------------------------------------------------------
__global__ __launch_bounds__(256) void aggregate(const int* __restrict__ start,
                                                 const int* __restrict__ pcol,
                                                 const float* __restrict__ pval,
                                                 const float* __restrict__ Y,
                                                 const float* __restrict__ b,
                                                 float* __restrict__ out, int n) {
    int row = blockIdx.x * 8 + (threadIdx.x >> 5);
    if (row >= n) return;
    int lane = threadIdx.x & 31;

    int s = start[row];
    int e = start[row + 1];
    float4 acc = ((const float4*)b)[lane];

    int i = s;
    for (; i + 4 <= e; i += 4) {  // 4 independent gathers in flight
        int c0 = pcol[i], c1 = pcol[i + 1], c2 = pcol[i + 2], c3 = pcol[i + 3];
        float v0 = pval[i], v1 = pval[i + 1], v2 = pval[i + 2], v3 = pval[i + 3];
        float4 y0 = *(const float4*)&Y[(long)c0 * D_C + lane * 4];
        float4 y1 = *(const float4*)&Y[(long)c1 * D_C + lane * 4];
        float4 y2 = *(const float4*)&Y[(long)c2 * D_C + lane * 4];
        float4 y3 = *(const float4*)&Y[(long)c3 * D_C + lane * 4];
        acc.x += v0 * y0.x + v1 * y1.x + v2 * y2.x + v3 * y3.x;
        acc.y += v0 * y0.y + v1 * y1.y + v2 * y2.y + v3 * y3.y;
        acc.z += v0 * y0.z + v1 * y1.z + v2 * y2.z + v3 * y3.z;
        acc.w += v0 * y0.w + v1 * y1.w + v2 * y2.w + v3 * y3.w;
    }
    for (; i < e; ++i) {
        int c0 = pcol[i];
        float v0 = pval[i];
        float4 y0 = *(const float4*)&Y[(long)c0 * D_C + lane * 4];
        acc.x += v0 * y0.x;
        acc.y += v0 * y0.y;
        acc.z += v0 * y0.z;
        acc.w += v0 * y0.w;
    }
    *(float4*)&out[(long)row * D_C + lane * 4] = acc;
}

// ---------------------------------------------------------------------------
// Fallback path (only if ws_size < CSR layout): round-1 atomic scatter.
// ---------------------------------------------------------------------------
__global__ __launch_bounds__(256) void init_out(const float* __restrict__ b,
                                                float* __restrict__ out, int n) {
    int idx = blockIdx.x * 256 + threadIdx.x;
    int total = n * (D_C / 4);
    if (idx < total) {
        int o4 = idx & (D_C / 4 - 1);
        ((float4*)out)[idx] = ((const float4*)b)[o4];
    }
}

__global__ __launch_bounds__(256) void scatter_edges(const int* __restrict__ rows,
                                                     const int* __restrict__ cols,
                                                     const float* __restrict__ vals,
                                                     const float* __restrict__ Y,
                                                     float* __restrict__ out, int E) {
    int e = blockIdx.x * 8 + (threadIdx.x >> 5);
    if (e >= E) return;
    int lane = threadIdx.x & 31;
    int row = rows[e];
    int col = cols[e];
    float v = vals[e];
    float4 y = *(const float4*)&Y[(long)col * D_C + lane * 4];
    float* dst = out + (long)row * D_C + lane * 4;
    unsafeAtomicAdd(dst + 0, v * y.x);
    unsafeAtomicAdd(dst + 1, v * y.y);
    unsafeAtomicAdd(dst + 2, v * y.z);
    unsafeAtomicAdd(dst + 3, v * y.w);
}

extern "C" void kernel_launch(void* const* d_in, const int* in_sizes, int n_in,
                              void* d_out, int out_size, void* d_ws, size_t ws_size,
                              hipStream_t stream) {
    const float* X  = (const float*)d_in[0];
    const int*   Ar = (const int*)d_in[1];
    const int*   Ac = (const int*)d_in[2];
    const float* Av = (const float*)d_in[3];
    const float* W  = (const float*)d_in[4];
    const float* b  = (const float*)d_in[5];
    float* out = (float*)d_out;

    // Workspace layout (4B elements):
    float* Y     = (float*)d_ws;            // 12,800,000 f32
    int* cnt     = (int*)(Y + 12800000);    // 100,096
    int* start   = cnt + 100096;            // 100,352 (N+1 used)
    int* cursor  = start + 100352;          // 100,096
    int* pcol    = cursor + 100096;         // 1,600,000
    float* pval  = (float*)(pcol + 1600000);// 1,600,000
    int* partial = (int*)(pval + 1600000);  // 512
    int* pscan   = partial + 512;           // 512
    size_t need  = (size_t)(12800000 + 100096 + 100352 + 100096 + 1600000 + 1600000 + 1024) * 4;

    // Y = X @ W^T (shared by both paths)
    gemm_xwt<<<(N_NODES_C + 63) / 64, 256, 0, stream>>>(X, W, Y, N_NODES_C);

    if (ws_size >= need) {
        // --- CSR build ---
        hipMemsetAsync(cnt, 0, N_NODES_C * sizeof(int), stream);
        hist_rows<<<(N_EDGES_C + 255) / 256, 256, 0, stream>>>(Ar, cnt, N_EDGES_C);
        block_sums<<<NB_SCAN, 256, 0, stream>>>(cnt, partial, N_NODES_C);
        scan_partials<<<1, 512, 0, stream>>>(partial, pscan, NB_SCAN);
        scan_block<<<NB_SCAN, 256, 0, stream>>>(cnt, pscan, start, cursor, N_NODES_C);
        fill_csr<<<(N_EDGES_C + 255) / 256, 256, 0, stream>>>(Ar, Ac, Av, cursor,
                                                              pcol, pval, N_EDGES_C);
        // --- pull aggregation, bias fused ---
        aggregate<<<(N_NODES_C + 7) / 8, 256, 0, stream>>>(start, pcol, pval, Y, b,
                                                           out, N_NODES_C);
    } else {
        // Fallback: atomic scatter (round-1 path)
        init_out<<<(N_NODES_C * (D_C / 4) + 255) / 256, 256, 0, stream>>>(b, out, N_NODES_C);
        scatter_edges<<<(N_EDGES_C + 7) / 8, 256, 0, stream>>>(Ar, Ac, Av, Y, out, N_EDGES_C);
    }
}

// Round 4
// 428.515 us; speedup vs baseline: 6.6657x; 1.0968x over previous
//
#include <hip/hip_runtime.h>

#define N_NODES_C 100000
#define N_EDGES_C 1600000
#define D_C 128
#define NB_SCAN ((N_NODES_C + 255) / 256)   // 391 blocks for the scan

// bf16 helpers (manual RNE pack; unpack is exact)
static __device__ __forceinline__ unsigned short f2bf(float x) {
    unsigned u = __float_as_uint(x);
    unsigned r = 0x7fffu + ((u >> 16) & 1u);
    return (unsigned short)((u + r) >> 16);
}
static __device__ __forceinline__ float bflo(unsigned u) { return __uint_as_float(u << 16); }
static __device__ __forceinline__ float bfhi(unsigned u) { return __uint_as_float(u & 0xffff0000u); }

// ---------------------------------------------------------------------------
// K1: Y = bf16(X @ W^T)   (W is [D_OUT, D_IN] row-major)
// ---------------------------------------------------------------------------
__global__ __launch_bounds__(256) void gemm_xwt(const float* __restrict__ X,
                                                const float* __restrict__ W,
                                                unsigned short* __restrict__ Y, int n) {
    __shared__ float Wt[128 * 132];  // Wt[k*132 + o] = W[o*128 + k]

    for (int idx = threadIdx.x; idx < 128 * 128; idx += 256) {
        int o = idx >> 7;
        int k = idx & 127;
        Wt[k * 132 + o] = W[idx];
    }
    __syncthreads();

    const int c = threadIdx.x & 31;   // cols 4c..4c+3
    const int r = threadIdx.x >> 5;   // rows r*8..r*8+7 within tile
    const long row0 = (long)blockIdx.x * 64;

    const float* xrow[8];
#pragma unroll
    for (int i = 0; i < 8; ++i) {
        long nr = row0 + r * 8 + i;
        if (nr >= n) nr = n - 1;
        xrow[i] = X + nr * D_C;
    }

    float acc[8][4];
#pragma unroll
    for (int i = 0; i < 8; ++i)
#pragma unroll
        for (int j = 0; j < 4; ++j) acc[i][j] = 0.f;

    for (int k4 = 0; k4 < 128; k4 += 4) {
        float4 w0 = *(const float4*)&Wt[(k4 + 0) * 132 + 4 * c];
        float4 w1 = *(const float4*)&Wt[(k4 + 1) * 132 + 4 * c];
        float4 w2 = *(const float4*)&Wt[(k4 + 2) * 132 + 4 * c];
        float4 w3 = *(const float4*)&Wt[(k4 + 3) * 132 + 4 * c];
#pragma unroll
        for (int i = 0; i < 8; ++i) {
            float4 xv = *(const float4*)&xrow[i][k4];
            acc[i][0] += xv.x * w0.x + xv.y * w1.x + xv.z * w2.x + xv.w * w3.x;
            acc[i][1] += xv.x * w0.y + xv.y * w1.y + xv.z * w2.y + xv.w * w3.y;
            acc[i][2] += xv.x * w0.z + xv.y * w1.z + xv.z * w2.z + xv.w * w3.z;
            acc[i][3] += xv.x * w0.w + xv.y * w1.w + xv.z * w2.w + xv.w * w3.w;
        }
    }

#pragma unroll
    for (int i = 0; i < 8; ++i) {
        long nr = row0 + r * 8 + i;
        if (nr < n) {
            uint2 u;
            u.x = (unsigned)f2bf(acc[i][0]) | ((unsigned)f2bf(acc[i][1]) << 16);
            u.y = (unsigned)f2bf(acc[i][2]) | ((unsigned)f2bf(acc[i][3]) << 16);
            *(uint2*)&Y[nr * D_C + 4 * c] = u;  // 8B aligned
        }
    }
}

// ---------------------------------------------------------------------------
// CSR build: histogram -> 3-kernel parallel scan -> bucket fill (fused int2)
// ---------------------------------------------------------------------------
__global__ __launch_bounds__(256) void hist_rows(const int* __restrict__ rows,
                                                 int* __restrict__ cnt, int E) {
    int e = blockIdx.x * 256 + threadIdx.x;
    if (e < E) atomicAdd(&cnt[rows[e]], 1);
}

__global__ __launch_bounds__(256) void block_sums(const int* __restrict__ cnt,
                                                  int* __restrict__ partial, int n) {
    __shared__ int buf[256];
    int i = blockIdx.x * 256 + threadIdx.x;
    buf[threadIdx.x] = (i < n) ? cnt[i] : 0;
    __syncthreads();
#pragma unroll
    for (int off = 128; off > 0; off >>= 1) {
        if (threadIdx.x < off) buf[threadIdx.x] += buf[threadIdx.x + off];
        __syncthreads();
    }
    if (threadIdx.x == 0) partial[blockIdx.x] = buf[0];
}

__global__ __launch_bounds__(512) void scan_partials(const int* __restrict__ partial,
                                                     int* __restrict__ pscan, int nb) {
    __shared__ int buf[512];
    int tid = threadIdx.x;
    int v = (tid < nb) ? partial[tid] : 0;
    buf[tid] = v;
    __syncthreads();
#pragma unroll
    for (int off = 1; off < 512; off <<= 1) {
        int t = (tid >= off) ? buf[tid - off] : 0;
        __syncthreads();
        buf[tid] += t;
        __syncthreads();
    }
    if (tid < nb) pscan[tid] = buf[tid] - v;  // exclusive
}

__global__ __launch_bounds__(256) void scan_block(const int* __restrict__ cnt,
                                                  const int* __restrict__ pscan,
                                                  int* __restrict__ start,
                                                  int* __restrict__ cursor, int n) {
    __shared__ int buf[256];
    int i = blockIdx.x * 256 + threadIdx.x;
    int tid = threadIdx.x;
    int v = (i < n) ? cnt[i] : 0;
    buf[tid] = v;
    __syncthreads();
#pragma unroll
    for (int off = 1; off < 256; off <<= 1) {
        int t = (tid >= off) ? buf[tid - off] : 0;
        __syncthreads();
        buf[tid] += t;
        __syncthreads();
    }
    int excl = buf[tid] - v + pscan[blockIdx.x];
    if (i < n) {
        start[i] = excl;
        cursor[i] = excl;
    }
    if (i == n - 1) start[n] = N_EDGES_C;
}

__global__ __launch_bounds__(256) void fill_csr(const int* __restrict__ rows,
                                                const int* __restrict__ cols,
                                                const float* __restrict__ vals,
                                                int* __restrict__ cursor,
                                                int2* __restrict__ pcv, int E) {
    int e = blockIdx.x * 256 + threadIdx.x;
    if (e >= E) return;
    int r = rows[e];
    int2 pv;
    pv.x = cols[e];
    pv.y = __float_as_int(vals[e]);
    int slot = atomicAdd(&cursor[r], 1);
    pcv[slot] = pv;  // one 8B scattered store per edge
}

// ---------------------------------------------------------------------------
// K3: pull aggregation. 16 lanes per row, 16B (8 bf16) per lane, unroll-4.
// out[row] = b + sum_{i in row} val[i] * Y[col[i]]
// ---------------------------------------------------------------------------
__global__ __launch_bounds__(256) void aggregate(const int* __restrict__ start,
                                                 const int2* __restrict__ pcv,
                                                 const unsigned short* __restrict__ Y,
                                                 const float* __restrict__ b,
                                                 float* __restrict__ out, int n) {
    int row = blockIdx.x * 16 + (threadIdx.x >> 4);
    if (row >= n) return;
    int lane = threadIdx.x & 15;

    int s = start[row];
    int e = start[row + 1];

    float acc[8];
    {
        float4 b0 = *(const float4*)&b[lane * 8];
        float4 b1 = *(const float4*)&b[lane * 8 + 4];
        acc[0] = b0.x; acc[1] = b0.y; acc[2] = b0.z; acc[3] = b0.w;
        acc[4] = b1.x; acc[5] = b1.y; acc[6] = b1.z; acc[7] = b1.w;
    }
    const unsigned short* Yl = Y + lane * 8;

    int i = s;
    for (; i + 4 <= e; i += 4) {  // 4 independent 16B gathers in flight
        int2 p0 = pcv[i], p1 = pcv[i + 1], p2 = pcv[i + 2], p3 = pcv[i + 3];
        uint4 y0 = *(const uint4*)&Yl[(long)p0.x * D_C];
        uint4 y1 = *(const uint4*)&Yl[(long)p1.x * D_C];
        uint4 y2 = *(const uint4*)&Yl[(long)p2.x * D_C];
        uint4 y3 = *(const uint4*)&Yl[(long)p3.x * D_C];
        float v0 = __int_as_float(p0.y), v1 = __int_as_float(p1.y);
        float v2 = __int_as_float(p2.y), v3 = __int_as_float(p3.y);
        acc[0] += v0 * bflo(y0.x) + v1 * bflo(y1.x) + v2 * bflo(y2.x) + v3 * bflo(y3.x);
        acc[1] += v0 * bfhi(y0.x) + v1 * bfhi(y1.x) + v2 * bfhi(y2.x) + v3 * bfhi(y3.x);
        acc[2] += v0 * bflo(y0.y) + v1 * bflo(y1.y) + v2 * bflo(y2.y) + v3 * bflo(y3.y);
        acc[3] += v0 * bfhi(y0.y) + v1 * bfhi(y1.y) + v2 * bfhi(y2.y) + v3 * bfhi(y3.y);
        acc[4] += v0 * bflo(y0.z) + v1 * bflo(y1.z) + v2 * bflo(y2.z) + v3 * bflo(y3.z);
        acc[5] += v0 * bfhi(y0.z) + v1 * bfhi(y1.z) + v2 * bfhi(y2.z) + v3 * bfhi(y3.z);
        acc[6] += v0 * bflo(y0.w) + v1 * bflo(y1.w) + v2 * bflo(y2.w) + v3 * bflo(y3.w);
        acc[7] += v0 * bfhi(y0.w) + v1 * bfhi(y1.w) + v2 * bfhi(y2.w) + v3 * bfhi(y3.w);
    }
    for (; i < e; ++i) {
        int2 p = pcv[i];
        uint4 y = *(const uint4*)&Yl[(long)p.x * D_C];
        float v = __int_as_float(p.y);
        acc[0] += v * bflo(y.x); acc[1] += v * bfhi(y.x);
        acc[2] += v * bflo(y.y); acc[3] += v * bfhi(y.y);
        acc[4] += v * bflo(y.z); acc[5] += v * bfhi(y.z);
        acc[6] += v * bflo(y.w); acc[7] += v * bfhi(y.w);
    }

    float4 o0 = make_float4(acc[0], acc[1], acc[2], acc[3]);
    float4 o1 = make_float4(acc[4], acc[5], acc[6], acc[7]);
    *(float4*)&out[(long)row * D_C + lane * 8] = o0;
    *(float4*)&out[(long)row * D_C + lane * 8 + 4] = o1;
}

// ---------------------------------------------------------------------------
// Fallback (ws too small): atomic scatter against bf16 Y.
// ---------------------------------------------------------------------------
__global__ __launch_bounds__(256) void init_out(const float* __restrict__ b,
                                                float* __restrict__ out, int n) {
    int idx = blockIdx.x * 256 + threadIdx.x;
    int total = n * (D_C / 4);
    if (idx < total) {
        int o4 = idx & (D_C / 4 - 1);
        ((float4*)out)[idx] = ((const float4*)b)[o4];
    }
}

__global__ __launch_bounds__(256) void scatter_edges(const int* __restrict__ rows,
                                                     const int* __restrict__ cols,
                                                     const float* __restrict__ vals,
                                                     const unsigned short* __restrict__ Y,
                                                     float* __restrict__ out, int E) {
    int e = blockIdx.x * 8 + (threadIdx.x >> 5);
    if (e >= E) return;
    int lane = threadIdx.x & 31;
    int row = rows[e];
    int col = cols[e];
    float v = vals[e];
    uint2 y = *(const uint2*)&Y[(long)col * D_C + lane * 4];
    float* dst = out + (long)row * D_C + lane * 4;
    unsafeAtomicAdd(dst + 0, v * bflo(y.x));
    unsafeAtomicAdd(dst + 1, v * bfhi(y.x));
    unsafeAtomicAdd(dst + 2, v * bflo(y.y));
    unsafeAtomicAdd(dst + 3, v * bfhi(y.y));
}

extern "C" void kernel_launch(void* const* d_in, const int* in_sizes, int n_in,
                              void* d_out, int out_size, void* d_ws, size_t ws_size,
                              hipStream_t stream) {
    const float* X  = (const float*)d_in[0];
    const int*   Ar = (const int*)d_in[1];
    const int*   Ac = (const int*)d_in[2];
    const float* Av = (const float*)d_in[3];
    const float* W  = (const float*)d_in[4];
    const float* b  = (const float*)d_in[5];
    float* out = (float*)d_out;

    // Workspace layout:
    unsigned short* Y = (unsigned short*)d_ws;  // 12,800,000 bf16 = 25.6 MB
    int* cnt     = (int*)(Y + 12800000);        // 100,096
    int* start   = cnt + 100096;                // 100,352 (N+1 used)
    int* cursor  = start + 100352;              // 100,096
    int2* pcv    = (int2*)(cursor + 100096);    // 1,600,000 int2 (col,valbits)
    int* partial = (int*)(pcv + 1600000);       // 512
    int* pscan   = partial + 512;               // 512
    size_t need = (size_t)12800000 * 2 +
                  (size_t)(100096 + 100352 + 100096 + 1024) * 4 +
                  (size_t)1600000 * 8;

    // Y = bf16(X @ W^T)  (shared by both paths)
    gemm_xwt<<<(N_NODES_C + 63) / 64, 256, 0, stream>>>(X, W, Y, N_NODES_C);

    if (ws_size >= need) {
        // --- CSR build ---
        hipMemsetAsync(cnt, 0, N_NODES_C * sizeof(int), stream);
        hist_rows<<<(N_EDGES_C + 255) / 256, 256, 0, stream>>>(Ar, cnt, N_EDGES_C);
        block_sums<<<NB_SCAN, 256, 0, stream>>>(cnt, partial, N_NODES_C);
        scan_partials<<<1, 512, 0, stream>>>(partial, pscan, NB_SCAN);
        scan_block<<<NB_SCAN, 256, 0, stream>>>(cnt, pscan, start, cursor, N_NODES_C);
        fill_csr<<<(N_EDGES_C + 255) / 256, 256, 0, stream>>>(Ar, Ac, Av, cursor,
                                                              pcv, N_EDGES_C);
        // --- pull aggregation, bias fused ---
        aggregate<<<(N_NODES_C + 15) / 16, 256, 0, stream>>>(start, pcv, Y, b,
                                                             out, N_NODES_C);
    } else {
        // Fallback: atomic scatter
        init_out<<<(N_NODES_C * (D_C / 4) + 255) / 256, 256, 0, stream>>>(b, out, N_NODES_C);
        scatter_edges<<<(N_EDGES_C + 7) / 8, 256, 0, stream>>>(Ar, Ac, Av, Y, out, N_EDGES_C);
    }
}

// Round 5
// 304.765 us; speedup vs baseline: 9.3723x; 1.4060x over previous
//
#include <hip/hip_runtime.h>

#define N_NODES_C 100000
#define N_EDGES_C 1600000
#define D_C 128
#define NBKT 256
#define RPB 391                                   // rows per bucket: ceil(100000/256)
#define PTILE 4096                                // edges per partition block
#define NPB ((N_EDGES_C + PTILE - 1) / PTILE)     // 391 partition blocks

// bf16 helpers (manual RNE pack; unpack is exact)
static __device__ __forceinline__ unsigned short f2bf(float x) {
    unsigned u = __float_as_uint(x);
    unsigned r = 0x7fffu + ((u >> 16) & 1u);
    return (unsigned short)((u + r) >> 16);
}
static __device__ __forceinline__ float bflo(unsigned u) { return __uint_as_float(u << 16); }
static __device__ __forceinline__ float bfhi(unsigned u) { return __uint_as_float(u & 0xffff0000u); }

// ---------------------------------------------------------------------------
// K1: Y = bf16(X @ W^T)   (W is [D_OUT, D_IN] row-major)
// ---------------------------------------------------------------------------
__global__ __launch_bounds__(256) void gemm_xwt(const float* __restrict__ X,
                                                const float* __restrict__ W,
                                                unsigned short* __restrict__ Y, int n) {
    __shared__ float Wt[128 * 132];  // Wt[k*132 + o] = W[o*128 + k]

    for (int idx = threadIdx.x; idx < 128 * 128; idx += 256) {
        int o = idx >> 7;
        int k = idx & 127;
        Wt[k * 132 + o] = W[idx];
    }
    __syncthreads();

    const int c = threadIdx.x & 31;   // cols 4c..4c+3
    const int r = threadIdx.x >> 5;   // rows r*8..r*8+7 within tile
    const long row0 = (long)blockIdx.x * 64;

    const float* xrow[8];
#pragma unroll
    for (int i = 0; i < 8; ++i) {
        long nr = row0 + r * 8 + i;
        if (nr >= n) nr = n - 1;
        xrow[i] = X + nr * D_C;
    }

    float acc[8][4];
#pragma unroll
    for (int i = 0; i < 8; ++i)
#pragma unroll
        for (int j = 0; j < 4; ++j) acc[i][j] = 0.f;

    for (int k4 = 0; k4 < 128; k4 += 4) {
        float4 w0 = *(const float4*)&Wt[(k4 + 0) * 132 + 4 * c];
        float4 w1 = *(const float4*)&Wt[(k4 + 1) * 132 + 4 * c];
        float4 w2 = *(const float4*)&Wt[(k4 + 2) * 132 + 4 * c];
        float4 w3 = *(const float4*)&Wt[(k4 + 3) * 132 + 4 * c];
#pragma unroll
        for (int i = 0; i < 8; ++i) {
            float4 xv = *(const float4*)&xrow[i][k4];
            acc[i][0] += xv.x * w0.x + xv.y * w1.x + xv.z * w2.x + xv.w * w3.x;
            acc[i][1] += xv.x * w0.y + xv.y * w1.y + xv.z * w2.y + xv.w * w3.y;
            acc[i][2] += xv.x * w0.z + xv.y * w1.z + xv.z * w2.z + xv.w * w3.z;
            acc[i][3] += xv.x * w0.w + xv.y * w1.w + xv.z * w2.w + xv.w * w3.w;
        }
    }

#pragma unroll
    for (int i = 0; i < 8; ++i) {
        long nr = row0 + r * 8 + i;
        if (nr < n) {
            uint2 u;
            u.x = (unsigned)f2bf(acc[i][0]) | ((unsigned)f2bf(acc[i][1]) << 16);
            u.y = (unsigned)f2bf(acc[i][2]) | ((unsigned)f2bf(acc[i][3]) << 16);
            *(uint2*)&Y[nr * D_C + 4 * c] = u;  // 8B aligned
        }
    }
}

// ---------------------------------------------------------------------------
// K2a: per-bucket edge histogram (LDS-staged, one global atomic per bucket/block)
// ---------------------------------------------------------------------------
__global__ __launch_bounds__(256) void hist_bucket(const int* __restrict__ rows,
                                                   int* __restrict__ bcnt, int E) {
    __shared__ int lh[NBKT];
    lh[threadIdx.x] = 0;
    __syncthreads();
    int stride = gridDim.x * 256;
    for (int e = blockIdx.x * 256 + threadIdx.x; e < E; e += stride)
        atomicAdd(&lh[rows[e] / RPB], 1);
    __syncthreads();
    int v = lh[threadIdx.x];
    if (v) atomicAdd(&bcnt[threadIdx.x], v);
}

// K2b: exclusive scan of 256 bucket counts -> bbase[257], gcursor copy
__global__ __launch_bounds__(256) void bucket_scan(const int* __restrict__ bcnt,
                                                   int* __restrict__ bbase,
                                                   int* __restrict__ gcursor) {
    __shared__ int buf[256];
    int tid = threadIdx.x;
    int v = bcnt[tid];
    buf[tid] = v;
    __syncthreads();
#pragma unroll
    for (int off = 1; off < 256; off <<= 1) {
        int t = (tid >= off) ? buf[tid - off] : 0;
        __syncthreads();
        buf[tid] += t;
        __syncthreads();
    }
    int excl = buf[tid] - v;
    bbase[tid] = excl;
    gcursor[tid] = excl;
    if (tid == 255) bbase[256] = buf[255];
}

// ---------------------------------------------------------------------------
// K2c: partition edges into 256 buckets, writes grouped per (block,bucket)
// so bursts are ~128B contiguous. Payload: (col | row_local<<17, val_bits).
// ---------------------------------------------------------------------------
__global__ __launch_bounds__(256) void partition(const int* __restrict__ rows,
                                                 const int* __restrict__ cols,
                                                 const float* __restrict__ vals,
                                                 int* __restrict__ gcursor,
                                                 int2* __restrict__ staging, int E) {
    __shared__ int lhist[NBKT];
    __shared__ int lbase[NBKT];
    __shared__ unsigned short ebkt[PTILE];
    __shared__ unsigned short ernk[PTILE];
    const int tid = threadIdx.x;
    const int t0 = blockIdx.x * PTILE;

    lhist[tid] = 0;
    __syncthreads();

#pragma unroll
    for (int k = 0; k < PTILE / 256; ++k) {
        int e = t0 + k * 256 + tid;
        if (e < E) {
            int bkt = rows[e] / RPB;
            int rnk = atomicAdd(&lhist[bkt], 1);
            ebkt[k * 256 + tid] = (unsigned short)bkt;
            ernk[k * 256 + tid] = (unsigned short)rnk;
        }
    }
    __syncthreads();

    lbase[tid] = lhist[tid] ? atomicAdd(&gcursor[tid], lhist[tid]) : 0;
    __syncthreads();

#pragma unroll
    for (int k = 0; k < PTILE / 256; ++k) {
        int e = t0 + k * 256 + tid;
        if (e < E) {
            int li = k * 256 + tid;
            int bkt = ebkt[li];
            int rl = rows[e] - bkt * RPB;   // rows[e] L1/L2-hot from phase 1
            int2 p;
            p.x = cols[e] | (rl << 17);
            p.y = __float_as_int(vals[e]);
            staging[lbase[bkt] + ernk[li]] = p;
        }
    }
}

// ---------------------------------------------------------------------------
// K2d: one block per bucket -> exact CSR. Computes per-row starts in LDS
// (hist + block scan over 391 rows), writes start[] and scatters the bucket's
// edges to exact slots. The bucket's output span is written by THIS block
// only -> single-XCD L2 assembles full lines -> ~1x writeback.
// ---------------------------------------------------------------------------
__global__ __launch_bounds__(512) void bucket_fill(const int* __restrict__ bbase,
                                                   const int2* __restrict__ staging,
                                                   int* __restrict__ start,
                                                   int2* __restrict__ pcv) {
    __shared__ int buf[512];
    __shared__ int lcur[512];
    const int b = blockIdx.x, tid = threadIdx.x;
    const int s = bbase[b], e = bbase[b + 1];

    buf[tid] = 0;
    __syncthreads();
    for (int i = s + tid; i < e; i += 512) {
        int rl = ((unsigned)staging[i].x) >> 17;
        atomicAdd(&buf[rl], 1);
    }
    __syncthreads();
    int v = buf[tid];
    // inclusive Hillis-Steele over 512 (rows >= RPB have count 0)
    for (int off = 1; off < 512; off <<= 1) {
        int t = (tid >= off) ? buf[tid - off] : 0;
        __syncthreads();
        buf[tid] += t;
        __syncthreads();
    }
    int grow = s + buf[tid] - v;   // bucket base + exclusive prefix
    lcur[tid] = grow;
    int row = b * RPB + tid;
    if (tid < RPB && row < N_NODES_C) start[row] = grow;
    if (b == NBKT - 1 && tid == 0) start[N_NODES_C] = N_EDGES_C;
    __syncthreads();

    for (int i = s + tid; i < e; i += 512) {
        int2 p = staging[i];
        int rl = ((unsigned)p.x) >> 17;
        int slot = atomicAdd(&lcur[rl], 1);
        pcv[slot] = p;
    }
}

// ---------------------------------------------------------------------------
// K3: pull aggregation. 16 lanes per row, 16B (8 bf16) per lane, unroll-4.
// out[row] = b + sum_{i in row} val[i] * Y[col[i]]   (col = p.x & 0x1FFFF)
// ---------------------------------------------------------------------------
__global__ __launch_bounds__(256) void aggregate(const int* __restrict__ start,
                                                 const int2* __restrict__ pcv,
                                                 const unsigned short* __restrict__ Y,
                                                 const float* __restrict__ b,
                                                 float* __restrict__ out, int n) {
    int row = blockIdx.x * 16 + (threadIdx.x >> 4);
    if (row >= n) return;
    int lane = threadIdx.x & 15;

    int s = start[row];
    int e = start[row + 1];

    float acc[8];
    {
        float4 b0 = *(const float4*)&b[lane * 8];
        float4 b1 = *(const float4*)&b[lane * 8 + 4];
        acc[0] = b0.x; acc[1] = b0.y; acc[2] = b0.z; acc[3] = b0.w;
        acc[4] = b1.x; acc[5] = b1.y; acc[6] = b1.z; acc[7] = b1.w;
    }
    const unsigned short* Yl = Y + lane * 8;

    int i = s;
    for (; i + 4 <= e; i += 4) {  // 4 independent 16B gathers in flight
        int2 p0 = pcv[i], p1 = pcv[i + 1], p2 = pcv[i + 2], p3 = pcv[i + 3];
        int c0 = p0.x & 0x1FFFF, c1 = p1.x & 0x1FFFF;
        int c2 = p2.x & 0x1FFFF, c3 = p3.x & 0x1FFFF;
        uint4 y0 = *(const uint4*)&Yl[(long)c0 * D_C];
        uint4 y1 = *(const uint4*)&Yl[(long)c1 * D_C];
        uint4 y2 = *(const uint4*)&Yl[(long)c2 * D_C];
        uint4 y3 = *(const uint4*)&Yl[(long)c3 * D_C];
        float v0 = __int_as_float(p0.y), v1 = __int_as_float(p1.y);
        float v2 = __int_as_float(p2.y), v3 = __int_as_float(p3.y);
        acc[0] += v0 * bflo(y0.x) + v1 * bflo(y1.x) + v2 * bflo(y2.x) + v3 * bflo(y3.x);
        acc[1] += v0 * bfhi(y0.x) + v1 * bfhi(y1.x) + v2 * bfhi(y2.x) + v3 * bfhi(y3.x);
        acc[2] += v0 * bflo(y0.y) + v1 * bflo(y1.y) + v2 * bflo(y2.y) + v3 * bflo(y3.y);
        acc[3] += v0 * bfhi(y0.y) + v1 * bfhi(y1.y) + v2 * bfhi(y2.y) + v3 * bfhi(y3.y);
        acc[4] += v0 * bflo(y0.z) + v1 * bflo(y1.z) + v2 * bflo(y2.z) + v3 * bflo(y3.z);
        acc[5] += v0 * bfhi(y0.z) + v1 * bfhi(y1.z) + v2 * bfhi(y2.z) + v3 * bfhi(y3.z);
        acc[6] += v0 * bflo(y0.w) + v1 * bflo(y1.w) + v2 * bflo(y2.w) + v3 * bflo(y3.w);
        acc[7] += v0 * bfhi(y0.w) + v1 * bfhi(y1.w) + v2 * bfhi(y2.w) + v3 * bfhi(y3.w);
    }
    for (; i < e; ++i) {
        int2 p = pcv[i];
        int c0 = p.x & 0x1FFFF;
        uint4 y = *(const uint4*)&Yl[(long)c0 * D_C];
        float v = __int_as_float(p.y);
        acc[0] += v * bflo(y.x); acc[1] += v * bfhi(y.x);
        acc[2] += v * bflo(y.y); acc[3] += v * bfhi(y.y);
        acc[4] += v * bflo(y.z); acc[5] += v * bfhi(y.z);
        acc[6] += v * bflo(y.w); acc[7] += v * bfhi(y.w);
    }

    float4 o0 = make_float4(acc[0], acc[1], acc[2], acc[3]);
    float4 o1 = make_float4(acc[4], acc[5], acc[6], acc[7]);
    *(float4*)&out[(long)row * D_C + lane * 8] = o0;
    *(float4*)&out[(long)row * D_C + lane * 8 + 4] = o1;
}

// ---------------------------------------------------------------------------
// Fallback (ws too small): atomic scatter against bf16 Y.
// ---------------------------------------------------------------------------
__global__ __launch_bounds__(256) void init_out(const float* __restrict__ b,
                                                float* __restrict__ out, int n) {
    int idx = blockIdx.x * 256 + threadIdx.x;
    int total = n * (D_C / 4);
    if (idx < total) {
        int o4 = idx & (D_C / 4 - 1);
        ((float4*)out)[idx] = ((const float4*)b)[o4];
    }
}

__global__ __launch_bounds__(256) void scatter_edges(const int* __restrict__ rows,
                                                     const int* __restrict__ cols,
                                                     const float* __restrict__ vals,
                                                     const unsigned short* __restrict__ Y,
                                                     float* __restrict__ out, int E) {
    int e = blockIdx.x * 8 + (threadIdx.x >> 5);
    if (e >= E) return;
    int lane = threadIdx.x & 31;
    int row = rows[e];
    int col = cols[e];
    float v = vals[e];
    uint2 y = *(const uint2*)&Y[(long)col * D_C + lane * 4];
    float* dst = out + (long)row * D_C + lane * 4;
    unsafeAtomicAdd(dst + 0, v * bflo(y.x));
    unsafeAtomicAdd(dst + 1, v * bfhi(y.x));
    unsafeAtomicAdd(dst + 2, v * bflo(y.y));
    unsafeAtomicAdd(dst + 3, v * bfhi(y.y));
}

extern "C" void kernel_launch(void* const* d_in, const int* in_sizes, int n_in,
                              void* d_out, int out_size, void* d_ws, size_t ws_size,
                              hipStream_t stream) {
    const float* X  = (const float*)d_in[0];
    const int*   Ar = (const int*)d_in[1];
    const int*   Ac = (const int*)d_in[2];
    const float* Av = (const float*)d_in[3];
    const float* W  = (const float*)d_in[4];
    const float* b  = (const float*)d_in[5];
    float* out = (float*)d_out;

    // Workspace layout:
    unsigned short* Y = (unsigned short*)d_ws;      // 12,800,000 bf16 = 25.6 MB
    int2* staging = (int2*)(Y + 12800000);          // 1,600,000 int2 (bucketed)
    int2* pcv     = staging + 1600000;              // 1,600,000 int2 (exact CSR)
    int* start    = (int*)(pcv + 1600000);          // 100,352 (N+1 used)
    int* bcnt     = start + 100352;                 // 256
    int* bbase    = bcnt + 256;                     // 257
    int* gcursor  = bbase + 257;                    // 256
    size_t need = (size_t)12800000 * 2 + (size_t)1600000 * 8 * 2 +
                  (size_t)(100352 + 256 + 257 + 256) * 4;

    // Y = bf16(X @ W^T)  (shared by both paths)
    gemm_xwt<<<(N_NODES_C + 63) / 64, 256, 0, stream>>>(X, W, Y, N_NODES_C);

    if (ws_size >= need) {
        hipMemsetAsync(bcnt, 0, NBKT * sizeof(int), stream);
        hist_bucket<<<NPB, 256, 0, stream>>>(Ar, bcnt, N_EDGES_C);
        bucket_scan<<<1, 256, 0, stream>>>(bcnt, bbase, gcursor);
        partition<<<NPB, 256, 0, stream>>>(Ar, Ac, Av, gcursor, staging, N_EDGES_C);
        bucket_fill<<<NBKT, 512, 0, stream>>>(bbase, staging, start, pcv);
        aggregate<<<(N_NODES_C + 15) / 16, 256, 0, stream>>>(start, pcv, Y, b,
                                                             out, N_NODES_C);
    } else {
        // Fallback: atomic scatter
        init_out<<<(N_NODES_C * (D_C / 4) + 255) / 256, 256, 0, stream>>>(b, out, N_NODES_C);
        scatter_edges<<<(N_EDGES_C + 7) / 8, 256, 0, stream>>>(Ar, Ac, Av, Y, out, N_EDGES_C);
    }
}

// Round 6
// 251.982 us; speedup vs baseline: 11.3355x; 1.2095x over previous
//
#include <hip/hip_runtime.h>

#define N_NODES_C 100000
#define N_EDGES_C 1600000
#define D_C 128
#define NBKT 256
#define RPB 391                                   // rows per bucket: ceil(100000/256)
#define PTILE 4096                                // edges per partition block
#define NPB ((N_EDGES_C + PTILE - 1) / PTILE)     // 391 partition blocks
#define WB_STRIDE 136                             // bf16 elems/row: 128 + 8 pad (272B, 16B-aligned)

// bf16 helpers (manual RNE pack; unpack is exact)
static __device__ __forceinline__ unsigned short f2bf(float x) {
    unsigned u = __float_as_uint(x);
    unsigned r = 0x7fffu + ((u >> 16) & 1u);
    return (unsigned short)((u + r) >> 16);
}
static __device__ __forceinline__ float bflo(unsigned u) { return __uint_as_float(u << 16); }
static __device__ __forceinline__ float bfhi(unsigned u) { return __uint_as_float(u & 0xffff0000u); }

typedef __attribute__((ext_vector_type(8))) __bf16 bf16x8;
typedef __attribute__((ext_vector_type(4))) float f32x4;
union FragU { uint4 u; bf16x8 b; };

// ---------------------------------------------------------------------------
// K1: Y = bf16(X @ W^T) via MFMA. 4 waves/block, 16 rows/wave, 64 rows/block.
// A[m=lane&15][k=quad*8+j]; B[n=lane&15][k=quad*8+j]; D: col=lane&15,
// row=quad*4+reg (verified gfx950 mappings).
// ---------------------------------------------------------------------------
__global__ __launch_bounds__(256) void gemm_mfma(const float* __restrict__ X,
                                                 const float* __restrict__ W,
                                                 unsigned short* __restrict__ Y, int n) {
    __shared__ unsigned short Wb[128 * WB_STRIDE];  // 34,816 B

    const int tid = threadIdx.x;
    const int wave = tid >> 6;
    const int lane = tid & 63;
    const int m16 = lane & 15;
    const int quad = lane >> 4;

    const int row0 = blockIdx.x * 64 + wave * 16;  // wave's 16-row base
    int row = row0 + m16;
    int rowc = (row < n) ? row : (n - 1);

    // Issue X loads early: 4 K-steps x 8 consecutive floats at quad*8 offset.
    float4 xv[4][2];
    const float* xp = X + (long)rowc * D_C + quad * 8;
#pragma unroll
    for (int s = 0; s < 4; ++s) {
        xv[s][0] = *(const float4*)(xp + s * 32);
        xv[s][1] = *(const float4*)(xp + s * 32 + 4);
    }

    // Stage W -> bf16 LDS (coalesced float4 reads, 8B packed LDS writes).
    for (int i = tid; i < 128 * 32; i += 256) {
        int o = i >> 5;
        int k4 = (i & 31) * 4;
        float4 w = *(const float4*)&W[o * 128 + k4];
        uint2 p;
        p.x = (unsigned)f2bf(w.x) | ((unsigned)f2bf(w.y) << 16);
        p.y = (unsigned)f2bf(w.z) | ((unsigned)f2bf(w.w) << 16);
        *(uint2*)&Wb[o * WB_STRIDE + k4] = p;
    }
    __syncthreads();

    // Pack A fragments (bf16 RNE).
    FragU a[4];
#pragma unroll
    for (int s = 0; s < 4; ++s) {
        a[s].u.x = (unsigned)f2bf(xv[s][0].x) | ((unsigned)f2bf(xv[s][0].y) << 16);
        a[s].u.y = (unsigned)f2bf(xv[s][0].z) | ((unsigned)f2bf(xv[s][0].w) << 16);
        a[s].u.z = (unsigned)f2bf(xv[s][1].x) | ((unsigned)f2bf(xv[s][1].y) << 16);
        a[s].u.w = (unsigned)f2bf(xv[s][1].z) | ((unsigned)f2bf(xv[s][1].w) << 16);
    }

    f32x4 acc[8];
#pragma unroll
    for (int t = 0; t < 8; ++t) acc[t] = (f32x4){0.f, 0.f, 0.f, 0.f};

#pragma unroll
    for (int s = 0; s < 4; ++s) {
#pragma unroll
        for (int t = 0; t < 8; ++t) {
            FragU bf;
            bf.u = *(const uint4*)&Wb[(t * 16 + m16) * WB_STRIDE + s * 32 + quad * 8];
            acc[t] = __builtin_amdgcn_mfma_f32_16x16x32_bf16(a[s].b, bf.b, acc[t], 0, 0, 0);
        }
    }

    // Epilogue: D row = quad*4 + reg, col = t*16 + m16.
#pragma unroll
    for (int t = 0; t < 8; ++t) {
#pragma unroll
        for (int r = 0; r < 4; ++r) {
            int orow = row0 + quad * 4 + r;
            if (orow < n) Y[(long)orow * D_C + t * 16 + m16] = f2bf(acc[t][r]);
        }
    }
}

// ---------------------------------------------------------------------------
// K2a: per-bucket edge histogram
// ---------------------------------------------------------------------------
__global__ __launch_bounds__(256) void hist_bucket(const int* __restrict__ rows,
                                                   int* __restrict__ bcnt, int E) {
    __shared__ int lh[NBKT];
    lh[threadIdx.x] = 0;
    __syncthreads();
    int stride = gridDim.x * 256;
    for (int e = blockIdx.x * 256 + threadIdx.x; e < E; e += stride)
        atomicAdd(&lh[rows[e] / RPB], 1);
    __syncthreads();
    int v = lh[threadIdx.x];
    if (v) atomicAdd(&bcnt[threadIdx.x], v);
}

// K2b: exclusive scan of 256 bucket counts -> bbase[257], gcursor copy
__global__ __launch_bounds__(256) void bucket_scan(const int* __restrict__ bcnt,
                                                   int* __restrict__ bbase,
                                                   int* __restrict__ gcursor) {
    __shared__ int buf[256];
    int tid = threadIdx.x;
    int v = bcnt[tid];
    buf[tid] = v;
    __syncthreads();
#pragma unroll
    for (int off = 1; off < 256; off <<= 1) {
        int t = (tid >= off) ? buf[tid - off] : 0;
        __syncthreads();
        buf[tid] += t;
        __syncthreads();
    }
    int excl = buf[tid] - v;
    bbase[tid] = excl;
    gcursor[tid] = excl;
    if (tid == 255) bbase[256] = buf[255];
}

// ---------------------------------------------------------------------------
// K2c: partition edges into 256 buckets, grouped writes per (block,bucket).
// Payload: (col | row_local<<17, val_bits).
// ---------------------------------------------------------------------------
__global__ __launch_bounds__(256) void partition(const int* __restrict__ rows,
                                                 const int* __restrict__ cols,
                                                 const float* __restrict__ vals,
                                                 int* __restrict__ gcursor,
                                                 int2* __restrict__ staging, int E) {
    __shared__ int lhist[NBKT];
    __shared__ int lbase[NBKT];
    __shared__ unsigned short ebkt[PTILE];
    __shared__ unsigned short ernk[PTILE];
    const int tid = threadIdx.x;
    const int t0 = blockIdx.x * PTILE;

    lhist[tid] = 0;
    __syncthreads();

#pragma unroll
    for (int k = 0; k < PTILE / 256; ++k) {
        int e = t0 + k * 256 + tid;
        if (e < E) {
            int bkt = rows[e] / RPB;
            int rnk = atomicAdd(&lhist[bkt], 1);
            ebkt[k * 256 + tid] = (unsigned short)bkt;
            ernk[k * 256 + tid] = (unsigned short)rnk;
        }
    }
    __syncthreads();

    lbase[tid] = lhist[tid] ? atomicAdd(&gcursor[tid], lhist[tid]) : 0;
    __syncthreads();

#pragma unroll
    for (int k = 0; k < PTILE / 256; ++k) {
        int e = t0 + k * 256 + tid;
        if (e < E) {
            int li = k * 256 + tid;
            int bkt = ebkt[li];
            int rl = rows[e] - bkt * RPB;
            int2 p;
            p.x = cols[e] | (rl << 17);
            p.y = __float_as_int(vals[e]);
            staging[lbase[bkt] + ernk[li]] = p;
        }
    }
}

// ---------------------------------------------------------------------------
// K2d: one block per bucket -> exact CSR (single-XCD line assembly).
// ---------------------------------------------------------------------------
__global__ __launch_bounds__(512) void bucket_fill(const int* __restrict__ bbase,
                                                   const int2* __restrict__ staging,
                                                   int* __restrict__ start,
                                                   int2* __restrict__ pcv) {
    __shared__ int buf[512];
    __shared__ int lcur[512];
    const int b = blockIdx.x, tid = threadIdx.x;
    const int s = bbase[b], e = bbase[b + 1];

    buf[tid] = 0;
    __syncthreads();
    for (int i = s + tid; i < e; i += 512) {
        int rl = ((unsigned)staging[i].x) >> 17;
        atomicAdd(&buf[rl], 1);
    }
    __syncthreads();
    int v = buf[tid];
    for (int off = 1; off < 512; off <<= 1) {
        int t = (tid >= off) ? buf[tid - off] : 0;
        __syncthreads();
        buf[tid] += t;
        __syncthreads();
    }
    int grow = s + buf[tid] - v;
    lcur[tid] = grow;
    int row = b * RPB + tid;
    if (tid < RPB && row < N_NODES_C) start[row] = grow;
    if (b == NBKT - 1 && tid == 0) start[N_NODES_C] = N_EDGES_C;
    __syncthreads();

    for (int i = s + tid; i < e; i += 512) {
        int2 p = staging[i];
        int rl = ((unsigned)p.x) >> 17;
        int slot = atomicAdd(&lcur[rl], 1);
        pcv[slot] = p;
    }
}

// ---------------------------------------------------------------------------
// K3: pull aggregation. 16 lanes per row, 16B (8 bf16) per lane, unroll-4.
// ---------------------------------------------------------------------------
__global__ __launch_bounds__(256) void aggregate(const int* __restrict__ start,
                                                 const int2* __restrict__ pcv,
                                                 const unsigned short* __restrict__ Y,
                                                 const float* __restrict__ b,
                                                 float* __restrict__ out, int n) {
    int row = blockIdx.x * 16 + (threadIdx.x >> 4);
    if (row >= n) return;
    int lane = threadIdx.x & 15;

    int s = start[row];
    int e = start[row + 1];

    float acc[8];
    {
        float4 b0 = *(const float4*)&b[lane * 8];
        float4 b1 = *(const float4*)&b[lane * 8 + 4];
        acc[0] = b0.x; acc[1] = b0.y; acc[2] = b0.z; acc[3] = b0.w;
        acc[4] = b1.x; acc[5] = b1.y; acc[6] = b1.z; acc[7] = b1.w;
    }
    const unsigned short* Yl = Y + lane * 8;

    int i = s;
    for (; i + 4 <= e; i += 4) {
        int2 p0 = pcv[i], p1 = pcv[i + 1], p2 = pcv[i + 2], p3 = pcv[i + 3];
        int c0 = p0.x & 0x1FFFF, c1 = p1.x & 0x1FFFF;
        int c2 = p2.x & 0x1FFFF, c3 = p3.x & 0x1FFFF;
        uint4 y0 = *(const uint4*)&Yl[(long)c0 * D_C];
        uint4 y1 = *(const uint4*)&Yl[(long)c1 * D_C];
        uint4 y2 = *(const uint4*)&Yl[(long)c2 * D_C];
        uint4 y3 = *(const uint4*)&Yl[(long)c3 * D_C];
        float v0 = __int_as_float(p0.y), v1 = __int_as_float(p1.y);
        float v2 = __int_as_float(p2.y), v3 = __int_as_float(p3.y);
        acc[0] += v0 * bflo(y0.x) + v1 * bflo(y1.x) + v2 * bflo(y2.x) + v3 * bflo(y3.x);
        acc[1] += v0 * bfhi(y0.x) + v1 * bfhi(y1.x) + v2 * bfhi(y2.x) + v3 * bfhi(y3.x);
        acc[2] += v0 * bflo(y0.y) + v1 * bflo(y1.y) + v2 * bflo(y2.y) + v3 * bflo(y3.y);
        acc[3] += v0 * bfhi(y0.y) + v1 * bfhi(y1.y) + v2 * bfhi(y2.y) + v3 * bfhi(y3.y);
        acc[4] += v0 * bflo(y0.z) + v1 * bflo(y1.z) + v2 * bflo(y2.z) + v3 * bflo(y3.z);
        acc[5] += v0 * bfhi(y0.z) + v1 * bfhi(y1.z) + v2 * bfhi(y2.z) + v3 * bfhi(y3.z);
        acc[6] += v0 * bflo(y0.w) + v1 * bflo(y1.w) + v2 * bflo(y2.w) + v3 * bflo(y3.w);
        acc[7] += v0 * bfhi(y0.w) + v1 * bfhi(y1.w) + v2 * bfhi(y2.w) + v3 * bfhi(y3.w);
    }
    for (; i < e; ++i) {
        int2 p = pcv[i];
        int c0 = p.x & 0x1FFFF;
        uint4 y = *(const uint4*)&Yl[(long)c0 * D_C];
        float v = __int_as_float(p.y);
        acc[0] += v * bflo(y.x); acc[1] += v * bfhi(y.x);
        acc[2] += v * bflo(y.y); acc[3] += v * bfhi(y.y);
        acc[4] += v * bflo(y.z); acc[5] += v * bfhi(y.z);
        acc[6] += v * bflo(y.w); acc[7] += v * bfhi(y.w);
    }

    float4 o0 = make_float4(acc[0], acc[1], acc[2], acc[3]);
    float4 o1 = make_float4(acc[4], acc[5], acc[6], acc[7]);
    *(float4*)&out[(long)row * D_C + lane * 8] = o0;
    *(float4*)&out[(long)row * D_C + lane * 8 + 4] = o1;
}

// ---------------------------------------------------------------------------
// Fallback (ws too small): atomic scatter against bf16 Y.
// ---------------------------------------------------------------------------
__global__ __launch_bounds__(256) void init_out(const float* __restrict__ b,
                                                float* __restrict__ out, int n) {
    int idx = blockIdx.x * 256 + threadIdx.x;
    int total = n * (D_C / 4);
    if (idx < total) {
        int o4 = idx & (D_C / 4 - 1);
        ((float4*)out)[idx] = ((const float4*)b)[o4];
    }
}

__global__ __launch_bounds__(256) void scatter_edges(const int* __restrict__ rows,
                                                     const int* __restrict__ cols,
                                                     const float* __restrict__ vals,
                                                     const unsigned short* __restrict__ Y,
                                                     float* __restrict__ out, int E) {
    int e = blockIdx.x * 8 + (threadIdx.x >> 5);
    if (e >= E) return;
    int lane = threadIdx.x & 31;
    int row = rows[e];
    int col = cols[e];
    float v = vals[e];
    uint2 y = *(const uint2*)&Y[(long)col * D_C + lane * 4];
    float* dst = out + (long)row * D_C + lane * 4;
    unsafeAtomicAdd(dst + 0, v * bflo(y.x));
    unsafeAtomicAdd(dst + 1, v * bfhi(y.x));
    unsafeAtomicAdd(dst + 2, v * bflo(y.y));
    unsafeAtomicAdd(dst + 3, v * bfhi(y.y));
}

extern "C" void kernel_launch(void* const* d_in, const int* in_sizes, int n_in,
                              void* d_out, int out_size, void* d_ws, size_t ws_size,
                              hipStream_t stream) {
    const float* X  = (const float*)d_in[0];
    const int*   Ar = (const int*)d_in[1];
    const int*   Ac = (const int*)d_in[2];
    const float* Av = (const float*)d_in[3];
    const float* W  = (const float*)d_in[4];
    const float* b  = (const float*)d_in[5];
    float* out = (float*)d_out;

    // Workspace layout:
    unsigned short* Y = (unsigned short*)d_ws;      // 12,800,000 bf16 = 25.6 MB
    int2* staging = (int2*)(Y + 12800000);          // 1,600,000 int2 (bucketed)
    int2* pcv     = staging + 1600000;              // 1,600,000 int2 (exact CSR)
    int* start    = (int*)(pcv + 1600000);          // 100,352 (N+1 used)
    int* bcnt     = start + 100352;                 // 256
    int* bbase    = bcnt + 256;                     // 257
    int* gcursor  = bbase + 257;                    // 256
    size_t need = (size_t)12800000 * 2 + (size_t)1600000 * 8 * 2 +
                  (size_t)(100352 + 256 + 257 + 256) * 4;

    // Y = bf16(X @ W^T) via MFMA (shared by both paths)
    gemm_mfma<<<(N_NODES_C + 63) / 64, 256, 0, stream>>>(X, W, Y, N_NODES_C);

    if (ws_size >= need) {
        hipMemsetAsync(bcnt, 0, NBKT * sizeof(int), stream);
        hist_bucket<<<NPB, 256, 0, stream>>>(Ar, bcnt, N_EDGES_C);
        bucket_scan<<<1, 256, 0, stream>>>(bcnt, bbase, gcursor);
        partition<<<NPB, 256, 0, stream>>>(Ar, Ac, Av, gcursor, staging, N_EDGES_C);
        bucket_fill<<<NBKT, 512, 0, stream>>>(bbase, staging, start, pcv);
        aggregate<<<(N_NODES_C + 15) / 16, 256, 0, stream>>>(start, pcv, Y, b,
                                                             out, N_NODES_C);
    } else {
        // Fallback: atomic scatter
        init_out<<<(N_NODES_C * (D_C / 4) + 255) / 256, 256, 0, stream>>>(b, out, N_NODES_C);
        scatter_edges<<<(N_EDGES_C + 7) / 8, 256, 0, stream>>>(Ar, Ac, Av, Y, out, N_EDGES_C);
    }
}

// Round 7
// 238.735 us; speedup vs baseline: 11.9645x; 1.0555x over previous
//
#include <hip/hip_runtime.h>

#define N_NODES_C 100000
#define N_EDGES_C 1600000
#define D_C 128
#define NBKT 512
#define RPB 196          // rows per bucket: ceil(100000/512)
#define CAP 4096         // per-bucket edge capacity (mean 3136, sigma 56 -> 17 sigma)
#define PTILE 4096       // edges per partition block
#define NPB ((N_EDGES_C + PTILE - 1) / PTILE)
#define WB_STRIDE 136    // bf16 elems/row in LDS W: 128 + 8 pad

// bf16 helpers (manual RNE pack; unpack is exact)
static __device__ __forceinline__ unsigned short f2bf(float x) {
    unsigned u = __float_as_uint(x);
    unsigned r = 0x7fffu + ((u >> 16) & 1u);
    return (unsigned short)((u + r) >> 16);
}
static __device__ __forceinline__ float bflo(unsigned u) { return __uint_as_float(u << 16); }
static __device__ __forceinline__ float bfhi(unsigned u) { return __uint_as_float(u & 0xffff0000u); }

typedef __attribute__((ext_vector_type(8))) __bf16 bf16x8;
typedef __attribute__((ext_vector_type(4))) float f32x4;
union FragU { uint4 u; bf16x8 b; };

// ---------------------------------------------------------------------------
// K1: Y = bf16(X @ W^T) via MFMA. 4 waves/block, 16 rows/wave, 64 rows/block.
// ---------------------------------------------------------------------------
__global__ __launch_bounds__(256) void gemm_mfma(const float* __restrict__ X,
                                                 const float* __restrict__ W,
                                                 unsigned short* __restrict__ Y, int n) {
    __shared__ unsigned short Wb[128 * WB_STRIDE];  // 34,816 B

    const int tid = threadIdx.x;
    const int wave = tid >> 6;
    const int lane = tid & 63;
    const int m16 = lane & 15;
    const int quad = lane >> 4;

    const int row0 = blockIdx.x * 64 + wave * 16;
    int row = row0 + m16;
    int rowc = (row < n) ? row : (n - 1);

    float4 xv[4][2];
    const float* xp = X + (long)rowc * D_C + quad * 8;
#pragma unroll
    for (int s = 0; s < 4; ++s) {
        xv[s][0] = *(const float4*)(xp + s * 32);
        xv[s][1] = *(const float4*)(xp + s * 32 + 4);
    }

    for (int i = tid; i < 128 * 32; i += 256) {
        int o = i >> 5;
        int k4 = (i & 31) * 4;
        float4 w = *(const float4*)&W[o * 128 + k4];
        uint2 p;
        p.x = (unsigned)f2bf(w.x) | ((unsigned)f2bf(w.y) << 16);
        p.y = (unsigned)f2bf(w.z) | ((unsigned)f2bf(w.w) << 16);
        *(uint2*)&Wb[o * WB_STRIDE + k4] = p;
    }
    __syncthreads();

    FragU a[4];
#pragma unroll
    for (int s = 0; s < 4; ++s) {
        a[s].u.x = (unsigned)f2bf(xv[s][0].x) | ((unsigned)f2bf(xv[s][0].y) << 16);
        a[s].u.y = (unsigned)f2bf(xv[s][0].z) | ((unsigned)f2bf(xv[s][0].w) << 16);
        a[s].u.z = (unsigned)f2bf(xv[s][1].x) | ((unsigned)f2bf(xv[s][1].y) << 16);
        a[s].u.w = (unsigned)f2bf(xv[s][1].z) | ((unsigned)f2bf(xv[s][1].w) << 16);
    }

    f32x4 acc[8];
#pragma unroll
    for (int t = 0; t < 8; ++t) acc[t] = (f32x4){0.f, 0.f, 0.f, 0.f};

#pragma unroll
    for (int s = 0; s < 4; ++s) {
#pragma unroll
        for (int t = 0; t < 8; ++t) {
            FragU bf;
            bf.u = *(const uint4*)&Wb[(t * 16 + m16) * WB_STRIDE + s * 32 + quad * 8];
            acc[t] = __builtin_amdgcn_mfma_f32_16x16x32_bf16(a[s].b, bf.b, acc[t], 0, 0, 0);
        }
    }

#pragma unroll
    for (int t = 0; t < 8; ++t) {
#pragma unroll
        for (int r = 0; r < 4; ++r) {
            int orow = row0 + quad * 4 + r;
            if (orow < n) Y[(long)orow * D_C + t * 16 + m16] = f2bf(acc[t][r]);
        }
    }
}

// ---------------------------------------------------------------------------
// K2: partition edges into 512 capped buckets (base = bkt*CAP, no scan needed).
// Grouped writes per (block,bucket). Payload: (col | row_local<<17, val_bits).
// ---------------------------------------------------------------------------
__global__ __launch_bounds__(256) void partition(const int* __restrict__ rows,
                                                 const int* __restrict__ cols,
                                                 const float* __restrict__ vals,
                                                 int* __restrict__ gcount,
                                                 int2* __restrict__ staging, int E) {
    __shared__ int lhist[NBKT];
    __shared__ int lbase[NBKT];
    __shared__ unsigned short ebkt[PTILE];
    __shared__ unsigned short ernk[PTILE];
    const int tid = threadIdx.x;
    const int t0 = blockIdx.x * PTILE;

    lhist[tid] = 0;
    lhist[tid + 256] = 0;
    __syncthreads();

#pragma unroll
    for (int k = 0; k < PTILE / 256; ++k) {
        int e = t0 + k * 256 + tid;
        if (e < E) {
            int bkt = rows[e] / RPB;
            int rnk = atomicAdd(&lhist[bkt], 1);
            ebkt[k * 256 + tid] = (unsigned short)bkt;
            ernk[k * 256 + tid] = (unsigned short)rnk;
        }
    }
    __syncthreads();

    lbase[tid] = lhist[tid] ? atomicAdd(&gcount[tid], lhist[tid]) : 0;
    lbase[tid + 256] = lhist[tid + 256] ? atomicAdd(&gcount[tid + 256], lhist[tid + 256]) : 0;
    __syncthreads();

#pragma unroll
    for (int k = 0; k < PTILE / 256; ++k) {
        int e = t0 + k * 256 + tid;
        if (e < E) {
            int li = k * 256 + tid;
            int bkt = ebkt[li];
            int rl = rows[e] - bkt * RPB;
            int2 p;
            p.x = cols[e] | (rl << 17);
            p.y = __float_as_int(vals[e]);
            staging[bkt * CAP + lbase[bkt] + ernk[li]] = p;
        }
    }
}

// ---------------------------------------------------------------------------
// K3: one block per bucket -> row-grouped edges in pcv[b*CAP ...], plus
// rbeg[row]/rcnt[row]. Single-XCD line assembly for the bucket span.
// ---------------------------------------------------------------------------
__global__ __launch_bounds__(256) void bucket_fill(const int* __restrict__ gcount,
                                                   const int2* __restrict__ staging,
                                                   int2* __restrict__ pcv,
                                                   int* __restrict__ rbeg,
                                                   int* __restrict__ rcnt) {
    __shared__ int hist[256];
    __shared__ int lcur[256];
    const int b = blockIdx.x, tid = threadIdx.x;
    const int cnt = gcount[b];
    const int s = b * CAP;

    hist[tid] = 0;
    __syncthreads();
    for (int i = tid; i < cnt; i += 256) {
        int rl = ((unsigned)staging[s + i].x) >> 17;
        atomicAdd(&hist[rl], 1);
    }
    __syncthreads();
    int v = hist[tid];
    // inclusive Hillis-Steele over 256 (rows >= RPB have count 0)
    for (int off = 1; off < 256; off <<= 1) {
        int t = (tid >= off) ? hist[tid - off] : 0;
        __syncthreads();
        hist[tid] += t;
        __syncthreads();
    }
    int excl = hist[tid] - v;
    lcur[tid] = s + excl;
    int row = b * RPB + tid;
    if (tid < RPB && row < N_NODES_C) {
        rbeg[row] = s + excl;
        rcnt[row] = v;
    }
    __syncthreads();

    for (int i = tid; i < cnt; i += 256) {
        int2 p = staging[s + i];
        int rl = ((unsigned)p.x) >> 17;
        int slot = atomicAdd(&lcur[rl], 1);
        pcv[slot] = p;
    }
}

// ---------------------------------------------------------------------------
// K4: pull aggregation. 16 lanes/row, 16B (8 bf16) per lane, unroll-8.
// out[row] = b + sum val*Y[col]   (col = p.x & 0x1FFFF)
// ---------------------------------------------------------------------------
__global__ __launch_bounds__(256) void aggregate(const int* __restrict__ rbeg,
                                                 const int* __restrict__ rcnt,
                                                 const int2* __restrict__ pcv,
                                                 const unsigned short* __restrict__ Y,
                                                 const float* __restrict__ b,
                                                 float* __restrict__ out, int n) {
    int row = blockIdx.x * 16 + (threadIdx.x >> 4);
    if (row >= n) return;
    int lane = threadIdx.x & 15;

    int s = rbeg[row];
    int e = s + rcnt[row];

    float acc[8];
    {
        float4 b0 = *(const float4*)&b[lane * 8];
        float4 b1 = *(const float4*)&b[lane * 8 + 4];
        acc[0] = b0.x; acc[1] = b0.y; acc[2] = b0.z; acc[3] = b0.w;
        acc[4] = b1.x; acc[5] = b1.y; acc[6] = b1.z; acc[7] = b1.w;
    }
    const unsigned short* Yl = Y + lane * 8;

    int i = s;
    for (; i + 8 <= e; i += 8) {  // 8 independent 256B gathers in flight
        int2 p[8];
        uint4 y[8];
#pragma unroll
        for (int u = 0; u < 8; ++u) p[u] = pcv[i + u];
#pragma unroll
        for (int u = 0; u < 8; ++u)
            y[u] = *(const uint4*)&Yl[(long)(p[u].x & 0x1FFFF) * D_C];
#pragma unroll
        for (int u = 0; u < 8; ++u) {
            float v = __int_as_float(p[u].y);
            acc[0] += v * bflo(y[u].x); acc[1] += v * bfhi(y[u].x);
            acc[2] += v * bflo(y[u].y); acc[3] += v * bfhi(y[u].y);
            acc[4] += v * bflo(y[u].z); acc[5] += v * bfhi(y[u].z);
            acc[6] += v * bflo(y[u].w); acc[7] += v * bfhi(y[u].w);
        }
    }
    for (; i + 4 <= e; i += 4) {
        int2 p[4];
        uint4 y[4];
#pragma unroll
        for (int u = 0; u < 4; ++u) p[u] = pcv[i + u];
#pragma unroll
        for (int u = 0; u < 4; ++u)
            y[u] = *(const uint4*)&Yl[(long)(p[u].x & 0x1FFFF) * D_C];
#pragma unroll
        for (int u = 0; u < 4; ++u) {
            float v = __int_as_float(p[u].y);
            acc[0] += v * bflo(y[u].x); acc[1] += v * bfhi(y[u].x);
            acc[2] += v * bflo(y[u].y); acc[3] += v * bfhi(y[u].y);
            acc[4] += v * bflo(y[u].z); acc[5] += v * bfhi(y[u].z);
            acc[6] += v * bflo(y[u].w); acc[7] += v * bfhi(y[u].w);
        }
    }
    for (; i < e; ++i) {
        int2 p = pcv[i];
        uint4 y = *(const uint4*)&Yl[(long)(p.x & 0x1FFFF) * D_C];
        float v = __int_as_float(p.y);
        acc[0] += v * bflo(y.x); acc[1] += v * bfhi(y.x);
        acc[2] += v * bflo(y.y); acc[3] += v * bfhi(y.y);
        acc[4] += v * bflo(y.z); acc[5] += v * bfhi(y.z);
        acc[6] += v * bflo(y.w); acc[7] += v * bfhi(y.w);
    }

    float4 o0 = make_float4(acc[0], acc[1], acc[2], acc[3]);
    float4 o1 = make_float4(acc[4], acc[5], acc[6], acc[7]);
    *(float4*)&out[(long)row * D_C + lane * 8] = o0;
    *(float4*)&out[(long)row * D_C + lane * 8 + 4] = o1;
}

// ---------------------------------------------------------------------------
// Fallback (ws too small): atomic scatter against bf16 Y.
// ---------------------------------------------------------------------------
__global__ __launch_bounds__(256) void init_out(const float* __restrict__ b,
                                                float* __restrict__ out, int n) {
    int idx = blockIdx.x * 256 + threadIdx.x;
    int total = n * (D_C / 4);
    if (idx < total) {
        int o4 = idx & (D_C / 4 - 1);
        ((float4*)out)[idx] = ((const float4*)b)[o4];
    }
}

__global__ __launch_bounds__(256) void scatter_edges(const int* __restrict__ rows,
                                                     const int* __restrict__ cols,
                                                     const float* __restrict__ vals,
                                                     const unsigned short* __restrict__ Y,
                                                     float* __restrict__ out, int E) {
    int e = blockIdx.x * 8 + (threadIdx.x >> 5);
    if (e >= E) return;
    int lane = threadIdx.x & 31;
    int row = rows[e];
    int col = cols[e];
    float v = vals[e];
    uint2 y = *(const uint2*)&Y[(long)col * D_C + lane * 4];
    float* dst = out + (long)row * D_C + lane * 4;
    unsafeAtomicAdd(dst + 0, v * bflo(y.x));
    unsafeAtomicAdd(dst + 1, v * bfhi(y.x));
    unsafeAtomicAdd(dst + 2, v * bflo(y.y));
    unsafeAtomicAdd(dst + 3, v * bfhi(y.y));
}

extern "C" void kernel_launch(void* const* d_in, const int* in_sizes, int n_in,
                              void* d_out, int out_size, void* d_ws, size_t ws_size,
                              hipStream_t stream) {
    const float* X  = (const float*)d_in[0];
    const int*   Ar = (const int*)d_in[1];
    const int*   Ac = (const int*)d_in[2];
    const float* Av = (const float*)d_in[3];
    const float* W  = (const float*)d_in[4];
    const float* b  = (const float*)d_in[5];
    float* out = (float*)d_out;

    // Workspace layout:
    unsigned short* Y = (unsigned short*)d_ws;        // 12,800,000 bf16 = 25.6 MB
    int2* staging = (int2*)(Y + 12800000);            // NBKT*CAP int2 = 16.8 MB
    int2* pcv     = staging + (size_t)NBKT * CAP;     // NBKT*CAP int2 = 16.8 MB
    int* rbeg     = (int*)(pcv + (size_t)NBKT * CAP); // 100,352
    int* rcnt     = rbeg + 100352;                    // 100,352
    int* gcount   = rcnt + 100352;                    // 512
    size_t need = (size_t)12800000 * 2 + (size_t)NBKT * CAP * 8 * 2 +
                  (size_t)(100352 * 2 + 512) * 4;

    // Y = bf16(X @ W^T) via MFMA (shared by both paths)
    gemm_mfma<<<(N_NODES_C + 63) / 64, 256, 0, stream>>>(X, W, Y, N_NODES_C);

    if (ws_size >= need) {
        hipMemsetAsync(gcount, 0, NBKT * sizeof(int), stream);
        partition<<<NPB, 256, 0, stream>>>(Ar, Ac, Av, gcount, staging, N_EDGES_C);
        bucket_fill<<<NBKT, 256, 0, stream>>>(gcount, staging, pcv, rbeg, rcnt);
        aggregate<<<(N_NODES_C + 15) / 16, 256, 0, stream>>>(rbeg, rcnt, pcv, Y, b,
                                                             out, N_NODES_C);
    } else {
        // Fallback: atomic scatter
        init_out<<<(N_NODES_C * (D_C / 4) + 255) / 256, 256, 0, stream>>>(b, out, N_NODES_C);
        scatter_edges<<<(N_EDGES_C + 7) / 8, 256, 0, stream>>>(Ar, Ac, Av, Y, out, N_EDGES_C);
    }
}